// Round 14
// baseline (3280.711 us; speedup 1.0000x reference)
//
#include <hip/hip_runtime.h>
#include <hip/hip_bf16.h>
#include <cstdint>

#define B_ 64
#define S_ 256
#define V_ 50000
#define NT_ 64
#define E_ 300
#define H_ 500
#define SOS_ 2

typedef __hip_bfloat16 bf16;
typedef unsigned short ushort_t;
typedef __attribute__((ext_vector_type(8))) __bf16 v8bf;
typedef __attribute__((ext_vector_type(4))) float f32x4;
typedef __attribute__((ext_vector_type(4))) unsigned int u32x4;

__device__ __forceinline__ float sigm(float x) { return 1.f / (1.f + __expf(-x)); }
__device__ __forceinline__ float tanh_fast(float x) {
    float xx = fminf(fmaxf(x, -15.f), 15.f);
    float e = __expf(2.f * xx);
    return (e - 1.f) / (e + 1.f);
}

__device__ __forceinline__ float bfu_to_f(ushort_t u) {
    unsigned int v = ((unsigned int)u) << 16;
    return __builtin_bit_cast(float, v);
}
__device__ __forceinline__ ushort_t f_to_bfu(float f) {
    return __builtin_bit_cast(ushort_t, __float2bfloat16(f));
}

// Coherent (MALL-served) accessors for cross-XCD h-state. PROVEN sc0 sc1 both
// sides (R7/R13). No scope shortcuts (R12 deadlock lesson).
__device__ __forceinline__ v8bf load16_coh(const ushort_t* p) {
    v8bf r;
    asm volatile("global_load_dwordx4 %0, %1, off sc0 sc1" : "=v"(r) : "v"(p) : "memory");
    return r;
}
__device__ __forceinline__ void store16_coh(ushort_t* p, u32x4 v) {
    asm volatile("global_store_dwordx4 %0, %1, off sc0 sc1" :: "v"(p), "v"(v) : "memory");
}

// ---------------- debug fallback: reveal ws_size via output ----------------
__global__ void dbg_kernel(float* out, float v) {
    if (threadIdx.x < 64) out[threadIdx.x] = v;
}

// ---------------- embedding gather (fp32 -> bf16 bits, K padded to 320) ----------------
__global__ void gather_kernel(const int* __restrict__ x, const float* __restrict__ embed,
                              ushort_t* __restrict__ h0) {
    int m = blockIdx.x;
    int tok = x[m];
    const float* src = embed + (size_t)tok * E_;
    ushort_t* dst = h0 + (size_t)m * 320;
    for (int e = threadIdx.x; e < 320; e += blockDim.x)
        dst[e] = (e < E_) ? f_to_bfu(src[e]) : (ushort_t)0;
}

// ---------------- weight fp32 -> bf16 with K remap/pad ----------------
__global__ void conv_w_kernel(const float* __restrict__ in, ushort_t* __restrict__ out,
                              int N, int Kout, int Kin, int split, int real) {
    int idx = blockIdx.x * 256 + threadIdx.x;
    if (idx >= N * Kout) return;
    int n = idx / Kout, k = idx % Kout;
    int half = (k >= split) ? 1 : 0;
    int ki = k - half * split;
    float v = (ki < real) ? in[(size_t)n * Kin + half * real + ki] : 0.f;
    out[idx] = f_to_bfu(v);
}

// ---------------- MFMA bf16 GEMM producing G[t][bgrp][n][16] ----------------
template <int AV>
__global__ __launch_bounds__(256) void gemm_mfma(const ushort_t* __restrict__ A,
                                                 const ushort_t* __restrict__ Wf,
                                                 const ushort_t* __restrict__ Wb,
                                                 const float* __restrict__ bf_,
                                                 const float* __restrict__ bb_,
                                                 ushort_t* __restrict__ Cf,
                                                 ushort_t* __restrict__ Cb,
                                                 int Nn, int Kp) {
    const ushort_t* W = blockIdx.z ? Wb : Wf;
    const float* bias = blockIdx.z ? bb_ : bf_;
    ushort_t* C = blockIdx.z ? Cb : Cf;
    const int t = blockIdx.x;
    const int n0 = blockIdx.y * 64;
    const int tid = threadIdx.x;
    const int lane = tid & 63;
    const int wv = tid >> 6;
    const int wn = wv & 1, wb = wv >> 1;
    const int l15 = lane & 15, kgrp = lane >> 4;

    __shared__ ushort_t wlds[64 * 64];

    const int rrow = tid >> 3, kc = tid & 7;
    const int rrow2 = (tid + 256) >> 3;

    auto load_tile = [&](int k0, v8bf* nxt) {
#pragma unroll
        for (int c = 0; c < 2; ++c) {
            int rr = c ? rrow2 : rrow;
            int n = n0 + rr, k = k0 + kc * 8;
            if (n < Nn) {
                nxt[c] = *(const v8bf*)(W + (size_t)n * Kp + k);
            } else {
                u32x4 z = {0u, 0u, 0u, 0u};
                nxt[c] = __builtin_bit_cast(v8bf, z);
            }
        }
    };

    f32x4 acc[2][2] = {};
    v8bf nxt[2];
    load_tile(0, nxt);

    for (int k0 = 0; k0 < Kp; k0 += 64) {
        if (k0) __syncthreads();
#pragma unroll
        for (int c = 0; c < 2; ++c) {
            int rr = c ? rrow2 : rrow;
            int off = (rr * 128 + kc * 16) ^ ((rr & 7) << 4);
            *(v8bf*)((char*)wlds + off) = nxt[c];
        }
        __syncthreads();
        if (k0 + 64 < Kp) load_tile(k0 + 64, nxt);

#pragma unroll
        for (int ks = 0; ks < 2; ++ks) {
            int kk = k0 + ks * 32 + kgrp * 8;
            int br0 = wb * 32 + l15;
            const ushort_t* pb0;
            const ushort_t* pb1;
            if (AV == 0) {
                pb0 = A + ((size_t)(br0 * 256 + t)) * 320 + kk;
                pb1 = A + ((size_t)((br0 + 16) * 256 + t)) * 320 + kk;
            } else {
                int dir = kk >> 9, kr = kk & 511;
                pb0 = A + (((size_t)(dir * B_ + br0) * S_) + t) * 512 + kr;
                pb1 = A + (((size_t)(dir * B_ + br0 + 16) * S_) + t) * 512 + kr;
            }
            v8bf b0v = *(const v8bf*)pb0;
            v8bf b1v = *(const v8bf*)pb1;
            int r0 = wn * 32 + l15;
            int aoff0 = (r0 * 128 + ks * 64 + kgrp * 16) ^ ((r0 & 7) << 4);
            int aoff1 = ((r0 + 16) * 128 + ks * 64 + kgrp * 16) ^ ((r0 & 7) << 4);
            v8bf a0 = *(const v8bf*)((const char*)wlds + aoff0);
            v8bf a1 = *(const v8bf*)((const char*)wlds + aoff1);
            acc[0][0] = __builtin_amdgcn_mfma_f32_16x16x32_bf16(a0, b0v, acc[0][0], 0, 0, 0);
            acc[0][1] = __builtin_amdgcn_mfma_f32_16x16x32_bf16(a0, b1v, acc[0][1], 0, 0, 0);
            acc[1][0] = __builtin_amdgcn_mfma_f32_16x16x32_bf16(a1, b0v, acc[1][0], 0, 0, 0);
            acc[1][1] = __builtin_amdgcn_mfma_f32_16x16x32_bf16(a1, b1v, acc[1][1], 0, 0, 0);
        }
    }

    // C[t][bgrp][n][16]
#pragma unroll
    for (int nsub = 0; nsub < 2; ++nsub) {
#pragma unroll
        for (int bsub = 0; bsub < 2; ++bsub) {
#pragma unroll
            for (int r = 0; r < 4; ++r) {
                int n = n0 + wn * 32 + nsub * 16 + kgrp * 4 + r;
                if (n < Nn) {
                    int bcol = wb * 32 + bsub * 16 + l15;
                    C[(((size_t)t * 4 + (bcol >> 4)) * Nn + n) * 16 + (bcol & 15)] =
                        f_to_bfu(acc[nsub][bsub][r] + bias[n]);
                }
            }
        }
    }
}

// ---------------- MFMA emit projection: emit[m][64] = h2 @ Wout^T + b ----------------
__global__ __launch_bounds__(256) void emit_mfma(const ushort_t* __restrict__ A,
                                                 const ushort_t* __restrict__ W,
                                                 const float* __restrict__ bias,
                                                 float* __restrict__ C) {
    const int t = blockIdx.x;
    const int tid = threadIdx.x;
    const int lane = tid & 63;
    const int wv = tid >> 6;
    const int wn = wv & 1, wb = wv >> 1;
    const int l15 = lane & 15, kgrp = lane >> 4;

    __shared__ ushort_t wlds[64 * 64];

    const int rrow = tid >> 3, kc = tid & 7;
    const int rrow2 = (tid + 256) >> 3;

    auto load_tile = [&](int k0, v8bf* nxt) {
#pragma unroll
        for (int c = 0; c < 2; ++c) {
            int rr = c ? rrow2 : rrow;
            nxt[c] = *(const v8bf*)(W + (size_t)rr * 1024 + k0 + kc * 8);
        }
    };

    f32x4 acc[2][2] = {};
    v8bf nxt[2];
    load_tile(0, nxt);

    for (int k0 = 0; k0 < 1024; k0 += 64) {
        if (k0) __syncthreads();
#pragma unroll
        for (int c = 0; c < 2; ++c) {
            int rr = c ? rrow2 : rrow;
            int off = (rr * 128 + kc * 16) ^ ((rr & 7) << 4);
            *(v8bf*)((char*)wlds + off) = nxt[c];
        }
        __syncthreads();
        if (k0 + 64 < 1024) load_tile(k0 + 64, nxt);

#pragma unroll
        for (int ks = 0; ks < 2; ++ks) {
            int kk = k0 + ks * 32 + kgrp * 8;
            int dir = kk >> 9, kr = kk & 511;
            int br0 = wb * 32 + l15;
            const ushort_t* pb0 = A + (((size_t)(dir * B_ + br0) * S_) + t) * 512 + kr;
            const ushort_t* pb1 = A + (((size_t)(dir * B_ + br0 + 16) * S_) + t) * 512 + kr;
            v8bf b0v = *(const v8bf*)pb0;
            v8bf b1v = *(const v8bf*)pb1;
            int r0 = wn * 32 + l15;
            int aoff0 = (r0 * 128 + ks * 64 + kgrp * 16) ^ ((r0 & 7) << 4);
            int aoff1 = ((r0 + 16) * 128 + ks * 64 + kgrp * 16) ^ ((r0 & 7) << 4);
            v8bf a0 = *(const v8bf*)((const char*)wlds + aoff0);
            v8bf a1 = *(const v8bf*)((const char*)wlds + aoff1);
            acc[0][0] = __builtin_amdgcn_mfma_f32_16x16x32_bf16(a0, b0v, acc[0][0], 0, 0, 0);
            acc[0][1] = __builtin_amdgcn_mfma_f32_16x16x32_bf16(a0, b1v, acc[0][1], 0, 0, 0);
            acc[1][0] = __builtin_amdgcn_mfma_f32_16x16x32_bf16(a1, b0v, acc[1][0], 0, 0, 0);
            acc[1][1] = __builtin_amdgcn_mfma_f32_16x16x32_bf16(a1, b1v, acc[1][1], 0, 0, 0);
        }
    }

#pragma unroll
    for (int nsub = 0; nsub < 2; ++nsub) {
#pragma unroll
        for (int bsub = 0; bsub < 2; ++bsub) {
            int n = wn * 32 + nsub * 16 + kgrp * 4;
            int bcol = wb * 32 + bsub * 16 + l15;
            float4 v;
            v.x = acc[nsub][bsub][0] + bias[n + 0];
            v.y = acc[nsub][bsub][1] + bias[n + 1];
            v.z = acc[nsub][bsub][2] + bias[n + 2];
            v.w = acc[nsub][bsub][3] + bias[n + 3];
            *(float4*)&C[((size_t)bcol * S_ + t) * 64 + n] = v;
        }
    }
}

// ---------------- K-split-4 persistent LSTM recurrence ----------------
// grid 128 x 256. Block = (dir, shard 0..15 of 32 cols, bgrp 0..3); 4 waves
// split K into quarters of 128. Each wave holds 128 gate-rows x 128 k of W_hh
// in 128 VGPRs. Row map: A-row r (of 128) -> gate g=r&3, col cj=((r>>2)&3)*8
// + (r>>4)  => wave0 lane (l15,kgrp) owns 8 CONSECUTIVE cols kgrp*8+rt with
// all 4 gates in the f32x4 (g=rr). One 16B h-store per lane.
// SYNC (R7-proven): h-store -> vmcnt(0) ack -> relaxed agent flag; consumer
// polls its K-quarter's 4 flags, loads h once. Fan-in per step: 16 flags.
// hseq: [2][B][S][512] (pads zero; pad cols force-stored 0). G: [t][4][2000][16].
__global__ __launch_bounds__(256, 1) void lstm_wave_kernel(
        const ushort_t* __restrict__ Gf, const ushort_t* __restrict__ Gb,
        const float* __restrict__ Whh_f, const float* __restrict__ Whh_b,
        ushort_t* __restrict__ hseq,
        int* __restrict__ flags) {
    const int bid = blockIdx.x;
    const int dir = bid >> 6;
    const int shard = (bid >> 2) & 15;
    const int bgrp = bid & 3;
    const int tid = threadIdx.x;
    const int w = tid >> 6;             // K-quarter 0..3
    const int lane = tid & 63;
    const int l15 = lane & 15, kgrp = lane >> 4;
    const int batch = bgrp * 16 + l15;
    const int n0c = shard * 32;
    const int domain = dir * 4 + bgrp;

    const ushort_t* G = dir ? Gb : Gf;
    const float* Whh = dir ? Whh_b : Whh_f;

    __shared__ float xlds[2][3][8][4][64];   // [parity][srcwave-1][rt][gate][lane]

    // ---- stage W_hh quarter-slice into 128 VGPRs ----
    // wreg[rt][ki]: lane row r = rt*16+l15 -> g=l15&3, cj=(l15>>2)*8+rt;
    // k = w*128 + ki*32 + kgrp*8 + e
    v8bf wreg[8][4];
    {
        int g = l15 & 3;
#pragma unroll
        for (int rt = 0; rt < 8; ++rt) {
            int col = n0c + (l15 >> 2) * 8 + rt;
            bool cok = col < H_;
            const float* wrow = Whh + ((size_t)g * H_ + (cok ? col : 0)) * H_;
#pragma unroll
            for (int ki = 0; ki < 4; ++ki) {
                union { ushort_t u[8]; v8bf v; } tmp;
#pragma unroll
                for (int e = 0; e < 8; ++e) {
                    int k = w * 128 + ki * 32 + kgrp * 8 + e;
                    tmp.u[e] = (cok && k < H_) ? f_to_bfu(wrow[k]) : (ushort_t)0;
                }
                wreg[rt][ki] = tmp.v;
            }
        }
    }

    float c[8] = {};

    for (int s = 0; s < S_; ++s) {
        const int tr = dir ? (S_ - 1 - s) : s;

        // G prefetch (wave 0 only; issued before the poll so HBM latency hides)
        float p[8][4];
        if (w == 0) {
#pragma unroll
            for (int rt = 0; rt < 8; ++rt) {
                int col = n0c + kgrp * 8 + rt;
                int colc = (col < H_) ? col : (H_ - 1);
#pragma unroll
                for (int g = 0; g < 4; ++g)
                    p[rt][g] = bfu_to_f(G[(((size_t)tr * 4 + bgrp) * 2000 + g * H_ + colc) * 16 + l15]);
            }
        }
        asm volatile("" ::: "memory");

        f32x4 acc[8] = {};
        if (s > 0) {
            // poll the 4 flags covering this wave's K-quarter (shards w*4..w*4+3)
            {
                const int need = s;
                int fi = domain * 16 + w * 4 + (lane & 3);
                while (true) {
                    int f = (lane < 4)
                        ? __hip_atomic_load(&flags[fi], __ATOMIC_RELAXED, __HIP_MEMORY_SCOPE_AGENT)
                        : need;
                    if (__all(f >= need)) break;
                    __builtin_amdgcn_s_sleep(1);
                }
            }
            asm volatile("" ::: "memory");

            // load h once (ack guarantees data visible before flag)
            const int trp = dir ? (tr + 1) : (tr - 1);
            const ushort_t* hrow = hseq + (((size_t)dir * B_ + batch) * S_ + trp) * 512 + w * 128;
            v8bf bfr[4];
#pragma unroll
            for (int ki = 0; ki < 4; ++ki)
                bfr[ki] = load16_coh(hrow + ki * 32 + kgrp * 8);
            asm volatile("s_waitcnt vmcnt(0)" ::: "memory");
            __builtin_amdgcn_sched_barrier(0);   // rule-18: no MFMA hoist above the wait

#pragma unroll
            for (int ki = 0; ki < 4; ++ki)
#pragma unroll
                for (int rt = 0; rt < 8; ++rt)
                    acc[rt] = __builtin_amdgcn_mfma_f32_16x16x32_bf16(wreg[rt][ki], bfr[ki], acc[rt], 0, 0, 0);
        }

        // merge partials: waves 1..3 -> LDS (parity buffer), barrier, wave 0 adds
        if (w > 0) {
#pragma unroll
            for (int rt = 0; rt < 8; ++rt)
#pragma unroll
                for (int r = 0; r < 4; ++r)
                    xlds[s & 1][w - 1][rt][r][lane] = acc[rt][r];
        }
        __syncthreads();

        if (w == 0) {
            ushort_t hv[8];
#pragma unroll
            for (int rt = 0; rt < 8; ++rt) {
                float gi = p[rt][0] + acc[rt][0];
                float gf = p[rt][1] + acc[rt][1];
                float gg = p[rt][2] + acc[rt][2];
                float go = p[rt][3] + acc[rt][3];
                if (s > 0) {
#pragma unroll
                    for (int q = 0; q < 3; ++q) {
                        gi += xlds[s & 1][q][rt][0][lane];
                        gf += xlds[s & 1][q][rt][1][lane];
                        gg += xlds[s & 1][q][rt][2][lane];
                        go += xlds[s & 1][q][rt][3][lane];
                    }
                }
                c[rt] = sigm(gf) * c[rt] + sigm(gi) * tanh_fast(gg);
                float h = sigm(go) * tanh_fast(c[rt]);
                int col = n0c + kgrp * 8 + rt;
                hv[rt] = (col < H_) ? f_to_bfu(h) : (ushort_t)0;  // pads stay 0
            }
            u32x4 pk;
            pk[0] = (unsigned)hv[0] | ((unsigned)hv[1] << 16);
            pk[1] = (unsigned)hv[2] | ((unsigned)hv[3] << 16);
            pk[2] = (unsigned)hv[4] | ((unsigned)hv[5] << 16);
            pk[3] = (unsigned)hv[6] | ((unsigned)hv[7] << 16);
            store16_coh(hseq + (((size_t)dir * B_ + batch) * S_ + tr) * 512 + n0c + kgrp * 8, pk);
            // ACK: drain h-stores so the flag can never outrun the data
            asm volatile("s_waitcnt vmcnt(0)" ::: "memory");
            if (lane == 0)
                __hip_atomic_store(&flags[domain * 16 + shard], s + 1,
                                   __ATOMIC_RELAXED, __HIP_MEMORY_SCOPE_AGENT);
        }
    }
}

// ---------------- CRF: partition + gold score, one block per batch ----------------
__global__ __launch_bounds__(256) void crf_kernel(const float* __restrict__ emit,
                                                  const float* __restrict__ trans,
                                                  const int* __restrict__ x,
                                                  const int* __restrict__ y0,
                                                  float* __restrict__ out) {
    const int b = blockIdx.x, tid = threadIdx.x;
    __shared__ float tr[64][65];
    __shared__ float sc[2][64];
    __shared__ float zsh;
    __shared__ float red[4];

    for (int e = tid; e < 4096; e += 256) tr[e >> 6][e & 63] = trans[e];
    if (tid < 64) sc[0][tid] = (tid == SOS_) ? 0.f : -10000.f;
    __syncthreads();

    const int i = tid >> 2, sub = tid & 3;
    int cur = 0;
    for (int t = 0; t < S_; ++t) {
        int m = x[b * S_ + t] > 0;
        float v[16];
        float vmax = -3.0e38f;
#pragma unroll
        for (int jj = 0; jj < 16; ++jj) {
            int j = (sub << 4) + jj;
            v[jj] = sc[cur][j] + tr[i][j];
            vmax = fmaxf(vmax, v[jj]);
        }
        vmax = fmaxf(vmax, __shfl_xor(vmax, 1, 64));
        vmax = fmaxf(vmax, __shfl_xor(vmax, 2, 64));
        float s = 0.f;
#pragma unroll
        for (int jj = 0; jj < 16; ++jj) s += __expf(v[jj] - vmax);
        s += __shfl_xor(s, 1, 64);
        s += __shfl_xor(s, 2, 64);
        float lse = vmax + __logf(s);
        float e_i = emit[((size_t)b * S_ + t) * NT_ + i];
        if (sub == 0) sc[cur ^ 1][i] = m ? (lse + e_i) : sc[cur][i];
        __syncthreads();
        cur ^= 1;
    }

    if (tid < 64) {
        float v2 = sc[cur][tid];
        float mz = v2;
        for (int d = 1; d < 64; d <<= 1) mz = fmaxf(mz, __shfl_xor(mz, d, 64));
        float sz = __expf(v2 - mz);
        for (int d = 1; d < 64; d <<= 1) sz += __shfl_xor(sz, d, 64);
        if (tid == 0) zsh = mz + __logf(sz);
    }
    __syncthreads();

    {
        int t = tid;
        int m = x[b * S_ + t] > 0;
        int yc = y0[b * S_ + t];
        int yp = t ? y0[b * S_ + t - 1] : SOS_;
        float term = m ? (emit[((size_t)b * S_ + t) * NT_ + yc] + tr[yc][yp]) : 0.f;
        for (int d = 1; d < 64; d <<= 1) term += __shfl_xor(term, d, 64);
        if ((tid & 63) == 0) red[tid >> 6] = term;
    }
    __syncthreads();
    if (tid == 0) out[b] = zsh - (red[0] + red[1] + red[2] + red[3]);
}

// ---------------- launcher ----------------
extern "C" void kernel_launch(void* const* d_in, const int* in_sizes, int n_in,
                              void* d_out, int out_size, void* d_ws, size_t ws_size,
                              hipStream_t stream) {
    const int* x = (const int*)d_in[0];
    const int* y0 = (const int*)d_in[1];
    const float* embed = (const float*)d_in[2];
    const float* w_ih_l0f = (const float*)d_in[3];
    const float* w_hh_l0f = (const float*)d_in[4];
    const float* b_l0f = (const float*)d_in[5];
    const float* w_ih_l0b = (const float*)d_in[6];
    const float* w_hh_l0b = (const float*)d_in[7];
    const float* b_l0b = (const float*)d_in[8];
    const float* w_ih_l1f = (const float*)d_in[9];
    const float* w_hh_l1f = (const float*)d_in[10];
    const float* b_l1f = (const float*)d_in[11];
    const float* w_ih_l1b = (const float*)d_in[12];
    const float* w_hh_l1b = (const float*)d_in[13];
    const float* b_l1b = (const float*)d_in[14];
    const float* W_out = (const float*)d_in[15];
    const float* b_out = (const float*)d_in[16];
    const float* trans = (const float*)d_in[17];
    float* outp = (float*)d_out;

    char* ws = (char*)d_ws;
    size_t off = 0;
    auto alloc = [&](size_t bytes) {
        void* p = ws + off;
        off += (bytes + 255) & ~(size_t)255;
        return p;
    };
    ushort_t* h0 = (ushort_t*)alloc((size_t)B_ * S_ * 320 * 2);            // 10.5 MB
    ushort_t* hseq = (ushort_t*)alloc((size_t)2 * B_ * S_ * 512 * 2);      // 33.6 MB
    float* emitb = (float*)alloc((size_t)B_ * S_ * NT_ * 4);               // 4.2 MB
    ushort_t* Gf = (ushort_t*)alloc((size_t)S_ * 2000 * 64 * 2);           // 65.5 MB [t][4][2000][16]
    ushort_t* Gb = (ushort_t*)alloc((size_t)S_ * 2000 * 64 * 2);           // 65.5 MB
    int* flags = (int*)alloc((size_t)2 * 256 * 4);                         // 2 KB
    (void)in_sizes; (void)n_in; (void)out_size;

    // aliased weight buffers (disjoint lifetimes):
    ushort_t* Wl0f = (ushort_t*)emitb;
    ushort_t* Wl0b = Wl0f + (size_t)2000 * 320;
    ushort_t* Wl1f = (ushort_t*)h0;
    ushort_t* Wl1b = Wl1f + (size_t)2000 * 1024;
    ushort_t* Wout = Wl1b + (size_t)2000 * 1024;

    if (off > ws_size) {
        dbg_kernel<<<1, 64, 0, stream>>>(outp, (float)(ws_size / 1048576.0));
        return;
    }

    const int M = B_ * S_;

    hipMemsetAsync(flags, 0, (size_t)2 * 256 * 4, stream);
    hipMemsetAsync(hseq, 0, (size_t)2 * B_ * S_ * 512 * 2, stream);  // pads must be 0

    gather_kernel<<<M, 128, 0, stream>>>(x, embed, h0);

    {
        int tot = 2000 * 320, nb = (tot + 255) / 256;
        conv_w_kernel<<<nb, 256, 0, stream>>>(w_ih_l0f, Wl0f, 2000, 320, 300, 320, 300);
        conv_w_kernel<<<nb, 256, 0, stream>>>(w_ih_l0b, Wl0b, 2000, 320, 300, 320, 300);
    }

    // layer 0 input GEMM (MFMA): G[t][bgrp][n][16]
    gemm_mfma<0><<<dim3(S_, 32, 2), 256, 0, stream>>>(
        h0, Wl0f, Wl0b, b_l0f, b_l0b, Gf, Gb, 2000, 320);

    {
        int tot = 2000 * 1024, nb = (tot + 255) / 256;
        conv_w_kernel<<<nb, 256, 0, stream>>>(w_ih_l1f, Wl1f, 2000, 1024, 1000, 512, 500);
        conv_w_kernel<<<nb, 256, 0, stream>>>(w_ih_l1b, Wl1b, 2000, 1024, 1000, 512, 500);
        int tot2 = 64 * 1024, nb2 = (tot2 + 255) / 256;
        conv_w_kernel<<<nb2, 256, 0, stream>>>(W_out, Wout, 64, 1024, 1000, 512, 500);
    }

    // layer 0 recurrence (K-split-4, ack+flag sync)
    lstm_wave_kernel<<<128, 256, 0, stream>>>(Gf, Gb, w_hh_l0f, w_hh_l0b, hseq, flags);

    // layer 1 input GEMM (MFMA, consumes layer-0 hseq)
    gemm_mfma<1><<<dim3(S_, 32, 2), 256, 0, stream>>>(
        hseq, Wl1f, Wl1b, b_l1f, b_l1b, Gf, Gb, 2000, 1024);

    // layer 1 recurrence (separate flag region)
    lstm_wave_kernel<<<128, 256, 0, stream>>>(Gf, Gb, w_hh_l1f, w_hh_l1b, hseq, flags + 256);

    // emit projection (MFMA, fp32 out)
    emit_mfma<<<S_, 256, 0, stream>>>(hseq, Wout, b_out, emitb);

    crf_kernel<<<B_, 256, 0, stream>>>(emitb, trans, x, y0, outp);
}

// Round 15
// 2779.999 us; speedup vs baseline: 1.1801x; 1.1801x over previous
//
#include <hip/hip_runtime.h>
#include <hip/hip_bf16.h>
#include <cstdint>

#define B_ 64
#define S_ 256
#define V_ 50000
#define NT_ 64
#define E_ 300
#define H_ 500
#define SOS_ 2

typedef __hip_bfloat16 bf16;
typedef unsigned short ushort_t;
typedef __attribute__((ext_vector_type(8))) __bf16 v8bf;
typedef __attribute__((ext_vector_type(4))) float f32x4;
typedef __attribute__((ext_vector_type(4))) unsigned int u32x4;

__device__ __forceinline__ float sigm(float x) { return 1.f / (1.f + __expf(-x)); }
__device__ __forceinline__ float tanh_fast(float x) {
    float xx = fminf(fmaxf(x, -15.f), 15.f);
    float e = __expf(2.f * xx);
    return (e - 1.f) / (e + 1.f);
}

__device__ __forceinline__ float bfu_to_f(ushort_t u) {
    unsigned int v = ((unsigned int)u) << 16;
    return __builtin_bit_cast(float, v);
}
__device__ __forceinline__ ushort_t f_to_bfu(float f) {
    return __builtin_bit_cast(ushort_t, __float2bfloat16(f));
}

// Coherent (MALL-served) accessors for cross-XCD h-state. PROVEN sc0 sc1 both
// sides (R7/R13). No scope shortcuts (R12 deadlock lesson).
__device__ __forceinline__ v8bf load16_coh(const ushort_t* p) {
    v8bf r;
    asm volatile("global_load_dwordx4 %0, %1, off sc0 sc1" : "=v"(r) : "v"(p) : "memory");
    return r;
}
__device__ __forceinline__ void store8_coh(ushort_t* p, uint2 v) {
    asm volatile("global_store_dwordx2 %0, %1, off sc0 sc1" :: "v"(p), "v"(v) : "memory");
}

// ---------------- debug fallback: reveal ws_size via output ----------------
__global__ void dbg_kernel(float* out, float v) {
    if (threadIdx.x < 64) out[threadIdx.x] = v;
}

// ---------------- embedding gather (fp32 -> bf16 bits, K padded to 320) ----------------
__global__ void gather_kernel(const int* __restrict__ x, const float* __restrict__ embed,
                              ushort_t* __restrict__ h0) {
    int m = blockIdx.x;
    int tok = x[m];
    const float* src = embed + (size_t)tok * E_;
    ushort_t* dst = h0 + (size_t)m * 320;
    for (int e = threadIdx.x; e < 320; e += blockDim.x)
        dst[e] = (e < E_) ? f_to_bfu(src[e]) : (ushort_t)0;
}

// ---------------- weight fp32 -> bf16 with K remap/pad ----------------
__global__ void conv_w_kernel(const float* __restrict__ in, ushort_t* __restrict__ out,
                              int N, int Kout, int Kin, int split, int real) {
    int idx = blockIdx.x * 256 + threadIdx.x;
    if (idx >= N * Kout) return;
    int n = idx / Kout, k = idx % Kout;
    int half = (k >= split) ? 1 : 0;
    int ki = k - half * split;
    float v = (ki < real) ? in[(size_t)n * Kin + half * real + ki] : 0.f;
    out[idx] = f_to_bfu(v);
}

// ---------------- MFMA bf16 GEMM producing G[t][bgrp][n][16] ----------------
// grid: dim3(S_, 16, 2); block 512 (8 waves: wn 0..3 x wb 0..1).
// Block tile: 128n x 64b at fixed t. W-tile (128x64, 16KB LDS, XOR-swizzled)
// double-buffered via regs: next tile prefetched during MFMA.
template <int AV>
__global__ __launch_bounds__(512) void gemm_mfma(const ushort_t* __restrict__ A,
                                                 const ushort_t* __restrict__ Wf,
                                                 const ushort_t* __restrict__ Wb,
                                                 const float* __restrict__ bf_,
                                                 const float* __restrict__ bb_,
                                                 ushort_t* __restrict__ Cf,
                                                 ushort_t* __restrict__ Cb,
                                                 int Nn, int Kp) {
    const ushort_t* W = blockIdx.z ? Wb : Wf;
    const float* bias = blockIdx.z ? bb_ : bf_;
    ushort_t* C = blockIdx.z ? Cb : Cf;
    const int t = blockIdx.x;
    const int n0 = blockIdx.y * 128;
    const int tid = threadIdx.x;
    const int lane = tid & 63;
    const int wv = tid >> 6;
    const int wn = wv & 3, wb = wv >> 2;
    const int l15 = lane & 15, kgrp = lane >> 4;

    __shared__ ushort_t wlds[128 * 64];   // 16 KB

    const int rrow = tid >> 3, kc = tid & 7;          // chunks 0..511
    const int rrow2 = (tid + 512) >> 3;               // chunks 512..1023

    auto load_tile = [&](int k0, v8bf* nxt) {
#pragma unroll
        for (int c = 0; c < 2; ++c) {
            int rr = c ? rrow2 : rrow;
            int n = n0 + rr, k = k0 + kc * 8;
            if (n < Nn) {
                nxt[c] = *(const v8bf*)(W + (size_t)n * Kp + k);
            } else {
                u32x4 z = {0u, 0u, 0u, 0u};
                nxt[c] = __builtin_bit_cast(v8bf, z);
            }
        }
    };

    f32x4 acc[2][2] = {};
    v8bf nxt[2];
    load_tile(0, nxt);

    for (int k0 = 0; k0 < Kp; k0 += 64) {
        if (k0) __syncthreads();
#pragma unroll
        for (int c = 0; c < 2; ++c) {
            int rr = c ? rrow2 : rrow;
            int off = (rr * 128 + kc * 16) ^ ((rr & 7) << 4);
            *(v8bf*)((char*)wlds + off) = nxt[c];
        }
        __syncthreads();
        if (k0 + 64 < Kp) load_tile(k0 + 64, nxt);

#pragma unroll
        for (int ks = 0; ks < 2; ++ks) {
            int kk = k0 + ks * 32 + kgrp * 8;
            int br0 = wb * 32 + l15;
            const ushort_t* pb0;
            const ushort_t* pb1;
            if (AV == 0) {
                pb0 = A + ((size_t)(br0 * 256 + t)) * 320 + kk;
                pb1 = A + ((size_t)((br0 + 16) * 256 + t)) * 320 + kk;
            } else {
                int dir = kk >> 9, kr = kk & 511;
                pb0 = A + (((size_t)(dir * B_ + br0) * S_) + t) * 512 + kr;
                pb1 = A + (((size_t)(dir * B_ + br0 + 16) * S_) + t) * 512 + kr;
            }
            v8bf b0v = *(const v8bf*)pb0;
            v8bf b1v = *(const v8bf*)pb1;
            int r0 = wn * 32 + l15;
            int aoff0 = (r0 * 128 + ks * 64 + kgrp * 16) ^ ((r0 & 7) << 4);
            int aoff1 = ((r0 + 16) * 128 + ks * 64 + kgrp * 16) ^ (((r0 + 16) & 7) << 4);
            v8bf a0 = *(const v8bf*)((const char*)wlds + aoff0);
            v8bf a1 = *(const v8bf*)((const char*)wlds + aoff1);
            acc[0][0] = __builtin_amdgcn_mfma_f32_16x16x32_bf16(a0, b0v, acc[0][0], 0, 0, 0);
            acc[0][1] = __builtin_amdgcn_mfma_f32_16x16x32_bf16(a0, b1v, acc[0][1], 0, 0, 0);
            acc[1][0] = __builtin_amdgcn_mfma_f32_16x16x32_bf16(a1, b0v, acc[1][0], 0, 0, 0);
            acc[1][1] = __builtin_amdgcn_mfma_f32_16x16x32_bf16(a1, b1v, acc[1][1], 0, 0, 0);
        }
    }

    // C[t][bgrp][n][16]
#pragma unroll
    for (int nsub = 0; nsub < 2; ++nsub) {
#pragma unroll
        for (int bsub = 0; bsub < 2; ++bsub) {
#pragma unroll
            for (int r = 0; r < 4; ++r) {
                int n = n0 + wn * 32 + nsub * 16 + kgrp * 4 + r;
                if (n < Nn) {
                    int bcol = wb * 32 + bsub * 16 + l15;
                    C[(((size_t)t * 4 + (bcol >> 4)) * Nn + n) * 16 + (bcol & 15)] =
                        f_to_bfu(acc[nsub][bsub][r] + bias[n]);
                }
            }
        }
    }
}

// ---------------- MFMA emit projection: emit[m][64] = h2 @ Wout^T + b ----------------
__global__ __launch_bounds__(256) void emit_mfma(const ushort_t* __restrict__ A,
                                                 const ushort_t* __restrict__ W,
                                                 const float* __restrict__ bias,
                                                 float* __restrict__ C) {
    const int t = blockIdx.x;
    const int tid = threadIdx.x;
    const int lane = tid & 63;
    const int wv = tid >> 6;
    const int wn = wv & 1, wb = wv >> 1;
    const int l15 = lane & 15, kgrp = lane >> 4;

    __shared__ ushort_t wlds[64 * 64];

    const int rrow = tid >> 3, kc = tid & 7;
    const int rrow2 = (tid + 256) >> 3;

    auto load_tile = [&](int k0, v8bf* nxt) {
#pragma unroll
        for (int c = 0; c < 2; ++c) {
            int rr = c ? rrow2 : rrow;
            nxt[c] = *(const v8bf*)(W + (size_t)rr * 1024 + k0 + kc * 8);
        }
    };

    f32x4 acc[2][2] = {};
    v8bf nxt[2];
    load_tile(0, nxt);

    for (int k0 = 0; k0 < 1024; k0 += 64) {
        if (k0) __syncthreads();
#pragma unroll
        for (int c = 0; c < 2; ++c) {
            int rr = c ? rrow2 : rrow;
            int off = (rr * 128 + kc * 16) ^ ((rr & 7) << 4);
            *(v8bf*)((char*)wlds + off) = nxt[c];
        }
        __syncthreads();
        if (k0 + 64 < 1024) load_tile(k0 + 64, nxt);

#pragma unroll
        for (int ks = 0; ks < 2; ++ks) {
            int kk = k0 + ks * 32 + kgrp * 8;
            int dir = kk >> 9, kr = kk & 511;
            int br0 = wb * 32 + l15;
            const ushort_t* pb0 = A + (((size_t)(dir * B_ + br0) * S_) + t) * 512 + kr;
            const ushort_t* pb1 = A + (((size_t)(dir * B_ + br0 + 16) * S_) + t) * 512 + kr;
            v8bf b0v = *(const v8bf*)pb0;
            v8bf b1v = *(const v8bf*)pb1;
            int r0 = wn * 32 + l15;
            int aoff0 = (r0 * 128 + ks * 64 + kgrp * 16) ^ ((r0 & 7) << 4);
            int aoff1 = ((r0 + 16) * 128 + ks * 64 + kgrp * 16) ^ ((r0 & 7) << 4);
            v8bf a0 = *(const v8bf*)((const char*)wlds + aoff0);
            v8bf a1 = *(const v8bf*)((const char*)wlds + aoff1);
            acc[0][0] = __builtin_amdgcn_mfma_f32_16x16x32_bf16(a0, b0v, acc[0][0], 0, 0, 0);
            acc[0][1] = __builtin_amdgcn_mfma_f32_16x16x32_bf16(a0, b1v, acc[0][1], 0, 0, 0);
            acc[1][0] = __builtin_amdgcn_mfma_f32_16x16x32_bf16(a1, b0v, acc[1][0], 0, 0, 0);
            acc[1][1] = __builtin_amdgcn_mfma_f32_16x16x32_bf16(a1, b1v, acc[1][1], 0, 0, 0);
        }
    }

#pragma unroll
    for (int nsub = 0; nsub < 2; ++nsub) {
#pragma unroll
        for (int bsub = 0; bsub < 2; ++bsub) {
            int n = wn * 32 + nsub * 16 + kgrp * 4;
            int bcol = wb * 32 + bsub * 16 + l15;
            float4 v;
            v.x = acc[nsub][bsub][0] + bias[n + 0];
            v.y = acc[nsub][bsub][1] + bias[n + 1];
            v.z = acc[nsub][bsub][2] + bias[n + 2];
            v.w = acc[nsub][bsub][3] + bias[n + 3];
            *(float4*)&C[((size_t)bcol * S_ + t) * 64 + n] = v;
        }
    }
}

// ---------------- K-split 2-wave persistent LSTM recurrence (R13 verbatim) ----------------
// grid 256 x 128 threads. Block = (dir, shard 0..31, bgrp 0..3); 2 waves split K.
// SYNC (R7-proven, fastest measured): producer h-store -> vmcnt(0) ack ->
// relaxed agent flag store; consumer polls flags then loads h ONCE.
__global__ __launch_bounds__(128, 1) void lstm_wave_kernel(
        const ushort_t* __restrict__ Gf, const ushort_t* __restrict__ Gb,
        const float* __restrict__ Whh_f, const float* __restrict__ Whh_b,
        ushort_t* __restrict__ hseq,
        int* __restrict__ flags) {
    const int bid = blockIdx.x;
    const int dir = bid >> 7;
    const int shard = (bid >> 2) & 31;
    const int bgrp = bid & 3;
    const int tid = threadIdx.x;
    const int w = tid >> 6;             // K-half
    const int lane = tid & 63;
    const int l15 = lane & 15, kgrp = lane >> 4;
    const int batch = bgrp * 16 + l15;
    const int n0c = shard * 16;
    const int domain = dir * 4 + bgrp;

    const ushort_t* G = dir ? Gb : Gf;
    const float* Whh = dir ? Whh_b : Whh_f;

    __shared__ float xlds[2][16][64];

    v8bf wreg[4][8];
    {
        int g = l15 & 3;
        int colbase = n0c + (l15 >> 2) * 4;
#pragma unroll
        for (int j = 0; j < 4; ++j) {
            int col = colbase + j;
            bool cok = col < H_;
            const float* wrow = Whh + ((size_t)g * H_ + (cok ? col : 0)) * H_;
#pragma unroll
            for (int ki = 0; ki < 8; ++ki) {
                union { ushort_t u[8]; v8bf v; } tmp;
#pragma unroll
                for (int e = 0; e < 8; ++e) {
                    int k = w * 256 + ki * 32 + kgrp * 8 + e;
                    tmp.u[e] = (cok && k < H_) ? f_to_bfu(wrow[k]) : (ushort_t)0;
                }
                wreg[j][ki] = tmp.v;
            }
        }
    }

    float c[4] = {0.f, 0.f, 0.f, 0.f};

    for (int s = 0; s < S_; ++s) {
        const int tr = dir ? (S_ - 1 - s) : s;

        float p[4][4];
        if (w == 0) {
#pragma unroll
            for (int j = 0; j < 4; ++j) {
                int col = n0c + kgrp * 4 + j;
                int colc = (col < H_) ? col : (H_ - 1);
#pragma unroll
                for (int g = 0; g < 4; ++g)
                    p[j][g] = bfu_to_f(G[(((size_t)tr * 4 + bgrp) * 2000 + g * H_ + colc) * 16 + l15]);
            }
        }
        asm volatile("" ::: "memory");

        f32x4 acc[4] = {};
        if (s > 0) {
            {
                const int need = s;
                int fi = domain * 32 + w * 16 + (lane & 15);
                while (true) {
                    int f = (lane < 16)
                        ? __hip_atomic_load(&flags[fi], __ATOMIC_RELAXED, __HIP_MEMORY_SCOPE_AGENT)
                        : need;
                    if (__all(f >= need)) break;
                    __builtin_amdgcn_s_sleep(1);
                }
            }
            asm volatile("" ::: "memory");

            const int trp = dir ? (tr + 1) : (tr - 1);
            const ushort_t* hrow = hseq + (((size_t)dir * B_ + batch) * S_ + trp) * 512 + w * 256;
            v8bf bfr[8];
#pragma unroll
            for (int ki = 0; ki < 8; ++ki)
                bfr[ki] = load16_coh(hrow + ki * 32 + kgrp * 8);
            asm volatile("s_waitcnt vmcnt(0)" ::: "memory");
            __builtin_amdgcn_sched_barrier(0);   // rule-18: no MFMA hoist above the wait

#pragma unroll
            for (int ki = 0; ki < 8; ++ki)
#pragma unroll
                for (int j = 0; j < 4; ++j)
                    acc[j] = __builtin_amdgcn_mfma_f32_16x16x32_bf16(wreg[j][ki], bfr[ki], acc[j], 0, 0, 0);
        }

        if (w == 1) {
#pragma unroll
            for (int j = 0; j < 4; ++j)
#pragma unroll
                for (int r = 0; r < 4; ++r)
                    xlds[s & 1][j * 4 + r][lane] = acc[j][r];
        }
        __syncthreads();

        if (w == 0) {
            ushort_t hv[4];
#pragma unroll
            for (int j = 0; j < 4; ++j) {
                float gi = p[j][0] + acc[j][0] + xlds[s & 1][j * 4 + 0][lane];
                float gf = p[j][1] + acc[j][1] + xlds[s & 1][j * 4 + 1][lane];
                float gg = p[j][2] + acc[j][2] + xlds[s & 1][j * 4 + 2][lane];
                float go = p[j][3] + acc[j][3] + xlds[s & 1][j * 4 + 3][lane];
                c[j] = sigm(gf) * c[j] + sigm(gi) * tanh_fast(gg);
                hv[j] = f_to_bfu(sigm(go) * tanh_fast(c[j]));
            }
            int colb = n0c + kgrp * 4;
            if (colb < H_) {
                uint2 pk;
                pk.x = (unsigned)hv[0] | ((unsigned)hv[1] << 16);
                pk.y = (unsigned)hv[2] | ((unsigned)hv[3] << 16);
                store8_coh(hseq + (((size_t)dir * B_ + batch) * S_ + tr) * 512 + colb, pk);
            }
            asm volatile("s_waitcnt vmcnt(0)" ::: "memory");
            if (lane == 0)
                __hip_atomic_store(&flags[domain * 32 + shard], s + 1,
                                   __ATOMIC_RELAXED, __HIP_MEMORY_SCOPE_AGENT);
        }
    }
}

// ---------------- CRF: partition + gold score, one block per batch ----------------
__global__ __launch_bounds__(256) void crf_kernel(const float* __restrict__ emit,
                                                  const float* __restrict__ trans,
                                                  const int* __restrict__ x,
                                                  const int* __restrict__ y0,
                                                  float* __restrict__ out) {
    const int b = blockIdx.x, tid = threadIdx.x;
    __shared__ float tr[64][65];
    __shared__ float sc[2][64];
    __shared__ float zsh;
    __shared__ float red[4];

    for (int e = tid; e < 4096; e += 256) tr[e >> 6][e & 63] = trans[e];
    if (tid < 64) sc[0][tid] = (tid == SOS_) ? 0.f : -10000.f;
    __syncthreads();

    const int i = tid >> 2, sub = tid & 3;
    int cur = 0;
    for (int t = 0; t < S_; ++t) {
        int m = x[b * S_ + t] > 0;
        float v[16];
        float vmax = -3.0e38f;
#pragma unroll
        for (int jj = 0; jj < 16; ++jj) {
            int j = (sub << 4) + jj;
            v[jj] = sc[cur][j] + tr[i][j];
            vmax = fmaxf(vmax, v[jj]);
        }
        vmax = fmaxf(vmax, __shfl_xor(vmax, 1, 64));
        vmax = fmaxf(vmax, __shfl_xor(vmax, 2, 64));
        float s = 0.f;
#pragma unroll
        for (int jj = 0; jj < 16; ++jj) s += __expf(v[jj] - vmax);
        s += __shfl_xor(s, 1, 64);
        s += __shfl_xor(s, 2, 64);
        float lse = vmax + __logf(s);
        float e_i = emit[((size_t)b * S_ + t) * NT_ + i];
        if (sub == 0) sc[cur ^ 1][i] = m ? (lse + e_i) : sc[cur][i];
        __syncthreads();
        cur ^= 1;
    }

    if (tid < 64) {
        float v2 = sc[cur][tid];
        float mz = v2;
        for (int d = 1; d < 64; d <<= 1) mz = fmaxf(mz, __shfl_xor(mz, d, 64));
        float sz = __expf(v2 - mz);
        for (int d = 1; d < 64; d <<= 1) sz += __shfl_xor(sz, d, 64);
        if (tid == 0) zsh = mz + __logf(sz);
    }
    __syncthreads();

    {
        int t = tid;
        int m = x[b * S_ + t] > 0;
        int yc = y0[b * S_ + t];
        int yp = t ? y0[b * S_ + t - 1] : SOS_;
        float term = m ? (emit[((size_t)b * S_ + t) * NT_ + yc] + tr[yc][yp]) : 0.f;
        for (int d = 1; d < 64; d <<= 1) term += __shfl_xor(term, d, 64);
        if ((tid & 63) == 0) red[tid >> 6] = term;
    }
    __syncthreads();
    if (tid == 0) out[b] = zsh - (red[0] + red[1] + red[2] + red[3]);
}

// ---------------- launcher ----------------
extern "C" void kernel_launch(void* const* d_in, const int* in_sizes, int n_in,
                              void* d_out, int out_size, void* d_ws, size_t ws_size,
                              hipStream_t stream) {
    const int* x = (const int*)d_in[0];
    const int* y0 = (const int*)d_in[1];
    const float* embed = (const float*)d_in[2];
    const float* w_ih_l0f = (const float*)d_in[3];
    const float* w_hh_l0f = (const float*)d_in[4];
    const float* b_l0f = (const float*)d_in[5];
    const float* w_ih_l0b = (const float*)d_in[6];
    const float* w_hh_l0b = (const float*)d_in[7];
    const float* b_l0b = (const float*)d_in[8];
    const float* w_ih_l1f = (const float*)d_in[9];
    const float* w_hh_l1f = (const float*)d_in[10];
    const float* b_l1f = (const float*)d_in[11];
    const float* w_ih_l1b = (const float*)d_in[12];
    const float* w_hh_l1b = (const float*)d_in[13];
    const float* b_l1b = (const float*)d_in[14];
    const float* W_out = (const float*)d_in[15];
    const float* b_out = (const float*)d_in[16];
    const float* trans = (const float*)d_in[17];
    float* outp = (float*)d_out;

    char* ws = (char*)d_ws;
    size_t off = 0;
    auto alloc = [&](size_t bytes) {
        void* p = ws + off;
        off += (bytes + 255) & ~(size_t)255;
        return p;
    };
    ushort_t* h0 = (ushort_t*)alloc((size_t)B_ * S_ * 320 * 2);            // 10.5 MB
    ushort_t* hseq = (ushort_t*)alloc((size_t)2 * B_ * S_ * 512 * 2);      // 33.6 MB
    float* emitb = (float*)alloc((size_t)B_ * S_ * NT_ * 4);               // 4.2 MB
    ushort_t* Gf = (ushort_t*)alloc((size_t)S_ * 2000 * 64 * 2);           // 65.5 MB [t][4][2000][16]
    ushort_t* Gb = (ushort_t*)alloc((size_t)S_ * 2000 * 64 * 2);           // 65.5 MB
    int* flags = (int*)alloc((size_t)2 * 256 * 4);                         // 2 KB
    (void)in_sizes; (void)n_in; (void)out_size;

    // aliased weight buffers (disjoint lifetimes):
    ushort_t* Wl0f = (ushort_t*)emitb;
    ushort_t* Wl0b = Wl0f + (size_t)2000 * 320;
    ushort_t* Wl1f = (ushort_t*)h0;
    ushort_t* Wl1b = Wl1f + (size_t)2000 * 1024;
    ushort_t* Wout = Wl1b + (size_t)2000 * 1024;

    if (off > ws_size) {
        dbg_kernel<<<1, 64, 0, stream>>>(outp, (float)(ws_size / 1048576.0));
        return;
    }

    const int M = B_ * S_;

    hipMemsetAsync(flags, 0, (size_t)2 * 256 * 4, stream);
    hipMemsetAsync(hseq, 0, (size_t)2 * B_ * S_ * 512 * 2, stream);  // pads must be 0

    gather_kernel<<<M, 128, 0, stream>>>(x, embed, h0);

    {
        int tot = 2000 * 320, nb = (tot + 255) / 256;
        conv_w_kernel<<<nb, 256, 0, stream>>>(w_ih_l0f, Wl0f, 2000, 320, 300, 320, 300);
        conv_w_kernel<<<nb, 256, 0, stream>>>(w_ih_l0b, Wl0b, 2000, 320, 300, 320, 300);
    }

    // layer 0 input GEMM (MFMA, 128n tile): G[t][bgrp][n][16]
    gemm_mfma<0><<<dim3(S_, 16, 2), 512, 0, stream>>>(
        h0, Wl0f, Wl0b, b_l0f, b_l0b, Gf, Gb, 2000, 320);

    {
        int tot = 2000 * 1024, nb = (tot + 255) / 256;
        conv_w_kernel<<<nb, 256, 0, stream>>>(w_ih_l1f, Wl1f, 2000, 1024, 1000, 512, 500);
        conv_w_kernel<<<nb, 256, 0, stream>>>(w_ih_l1b, Wl1b, 2000, 1024, 1000, 512, 500);
        int tot2 = 64 * 1024, nb2 = (tot2 + 255) / 256;
        conv_w_kernel<<<nb2, 256, 0, stream>>>(W_out, Wout, 64, 1024, 1000, 512, 500);
    }

    // layer 0 recurrence (R13 config, ack+flag sync)
    lstm_wave_kernel<<<256, 128, 0, stream>>>(Gf, Gb, w_hh_l0f, w_hh_l0b, hseq, flags);

    // layer 1 input GEMM (MFMA, 128n tile, consumes layer-0 hseq)
    gemm_mfma<1><<<dim3(S_, 16, 2), 512, 0, stream>>>(
        hseq, Wl1f, Wl1b, b_l1f, b_l1b, Gf, Gb, 2000, 1024);

    // layer 1 recurrence (separate flag region)
    lstm_wave_kernel<<<256, 128, 0, stream>>>(Gf, Gb, w_hh_l1f, w_hh_l1b, hseq, flags + 256);

    // emit projection (MFMA, fp32 out)
    emit_mfma<<<S_, 256, 0, stream>>>(hseq, Wout, b_out, emitb);

    crf_kernel<<<B_, 256, 0, stream>>>(emitb, trans, x, y0, outp);
}

// Round 16
// 2737.522 us; speedup vs baseline: 1.1984x; 1.0155x over previous
//
#include <hip/hip_runtime.h>
#include <hip/hip_bf16.h>
#include <cstdint>

#define B_ 64
#define S_ 256
#define V_ 50000
#define NT_ 64
#define E_ 300
#define H_ 500
#define SOS_ 2

typedef __hip_bfloat16 bf16;
typedef unsigned short ushort_t;
typedef __attribute__((ext_vector_type(8))) __bf16 v8bf;
typedef __attribute__((ext_vector_type(4))) float f32x4;
typedef __attribute__((ext_vector_type(4))) unsigned int u32x4;

__device__ __forceinline__ float sigm(float x) { return 1.f / (1.f + __expf(-x)); }
__device__ __forceinline__ float tanh_fast(float x) {
    float xx = fminf(fmaxf(x, -15.f), 15.f);
    float e = __expf(2.f * xx);
    return (e - 1.f) / (e + 1.f);
}

__device__ __forceinline__ float bfu_to_f(ushort_t u) {
    unsigned int v = ((unsigned int)u) << 16;
    return __builtin_bit_cast(float, v);
}
__device__ __forceinline__ ushort_t f_to_bfu(float f) {
    return __builtin_bit_cast(ushort_t, __float2bfloat16(f));
}

// Coherent (MALL-served) accessors for cross-XCD h-state. PROVEN sc0 sc1 both
// sides (R7/R13). No scope shortcuts (R12 deadlock lesson).
__device__ __forceinline__ v8bf load16_coh(const ushort_t* p) {
    v8bf r;
    asm volatile("global_load_dwordx4 %0, %1, off sc0 sc1" : "=v"(r) : "v"(p) : "memory");
    return r;
}
__device__ __forceinline__ void store8_coh(ushort_t* p, uint2 v) {
    asm volatile("global_store_dwordx2 %0, %1, off sc0 sc1" :: "v"(p), "v"(v) : "memory");
}

// ---------------- debug fallback: reveal ws_size via output ----------------
__global__ void dbg_kernel(float* out, float v) {
    if (threadIdx.x < 64) out[threadIdx.x] = v;
}

// ---------------- embedding gather (fp32 -> bf16 bits, K padded to 320) ----------------
__global__ void gather_kernel(const int* __restrict__ x, const float* __restrict__ embed,
                              ushort_t* __restrict__ h0) {
    int m = blockIdx.x;
    int tok = x[m];
    const float* src = embed + (size_t)tok * E_;
    ushort_t* dst = h0 + (size_t)m * 320;
    for (int e = threadIdx.x; e < 320; e += blockDim.x)
        dst[e] = (e < E_) ? f_to_bfu(src[e]) : (ushort_t)0;
}

// ---------------- weight fp32 -> bf16 with K remap/pad ----------------
__global__ void conv_w_kernel(const float* __restrict__ in, ushort_t* __restrict__ out,
                              int N, int Kout, int Kin, int split, int real) {
    int idx = blockIdx.x * 256 + threadIdx.x;
    if (idx >= N * Kout) return;
    int n = idx / Kout, k = idx % Kout;
    int half = (k >= split) ? 1 : 0;
    int ki = k - half * split;
    float v = (ki < real) ? in[(size_t)n * Kin + half * real + ki] : 0.f;
    out[idx] = f_to_bfu(v);
}

// ---------------- MFMA bf16 GEMM producing G[t][bgrp][n][16] ----------------
// grid: dim3(S_, 32, 2); block 256 (4 waves). Block tile: 64n x 64b at fixed t.
// W-tile double-buffered: next 64x64 tile prefetched to regs during MFMA.
// (R13 configuration -- measured best; 128n/512-thread variant was neutral-minus.)
template <int AV>
__global__ __launch_bounds__(256) void gemm_mfma(const ushort_t* __restrict__ A,
                                                 const ushort_t* __restrict__ Wf,
                                                 const ushort_t* __restrict__ Wb,
                                                 const float* __restrict__ bf_,
                                                 const float* __restrict__ bb_,
                                                 ushort_t* __restrict__ Cf,
                                                 ushort_t* __restrict__ Cb,
                                                 int Nn, int Kp) {
    const ushort_t* W = blockIdx.z ? Wb : Wf;
    const float* bias = blockIdx.z ? bb_ : bf_;
    ushort_t* C = blockIdx.z ? Cb : Cf;
    const int t = blockIdx.x;
    const int n0 = blockIdx.y * 64;
    const int tid = threadIdx.x;
    const int lane = tid & 63;
    const int wv = tid >> 6;
    const int wn = wv & 1, wb = wv >> 1;
    const int l15 = lane & 15, kgrp = lane >> 4;

    __shared__ ushort_t wlds[64 * 64];

    const int rrow = tid >> 3, kc = tid & 7;
    const int rrow2 = (tid + 256) >> 3;

    auto load_tile = [&](int k0, v8bf* nxt) {
#pragma unroll
        for (int c = 0; c < 2; ++c) {
            int rr = c ? rrow2 : rrow;
            int n = n0 + rr, k = k0 + kc * 8;
            if (n < Nn) {
                nxt[c] = *(const v8bf*)(W + (size_t)n * Kp + k);
            } else {
                u32x4 z = {0u, 0u, 0u, 0u};
                nxt[c] = __builtin_bit_cast(v8bf, z);
            }
        }
    };

    f32x4 acc[2][2] = {};
    v8bf nxt[2];
    load_tile(0, nxt);

    for (int k0 = 0; k0 < Kp; k0 += 64) {
        if (k0) __syncthreads();
#pragma unroll
        for (int c = 0; c < 2; ++c) {
            int rr = c ? rrow2 : rrow;
            int off = (rr * 128 + kc * 16) ^ ((rr & 7) << 4);
            *(v8bf*)((char*)wlds + off) = nxt[c];
        }
        __syncthreads();
        if (k0 + 64 < Kp) load_tile(k0 + 64, nxt);

#pragma unroll
        for (int ks = 0; ks < 2; ++ks) {
            int kk = k0 + ks * 32 + kgrp * 8;
            int br0 = wb * 32 + l15;
            const ushort_t* pb0;
            const ushort_t* pb1;
            if (AV == 0) {
                pb0 = A + ((size_t)(br0 * 256 + t)) * 320 + kk;
                pb1 = A + ((size_t)((br0 + 16) * 256 + t)) * 320 + kk;
            } else {
                int dir = kk >> 9, kr = kk & 511;
                pb0 = A + (((size_t)(dir * B_ + br0) * S_) + t) * 512 + kr;
                pb1 = A + (((size_t)(dir * B_ + br0 + 16) * S_) + t) * 512 + kr;
            }
            v8bf b0v = *(const v8bf*)pb0;
            v8bf b1v = *(const v8bf*)pb1;
            int r0 = wn * 32 + l15;
            int aoff0 = (r0 * 128 + ks * 64 + kgrp * 16) ^ ((r0 & 7) << 4);
            int aoff1 = ((r0 + 16) * 128 + ks * 64 + kgrp * 16) ^ ((r0 & 7) << 4);
            v8bf a0 = *(const v8bf*)((const char*)wlds + aoff0);
            v8bf a1 = *(const v8bf*)((const char*)wlds + aoff1);
            acc[0][0] = __builtin_amdgcn_mfma_f32_16x16x32_bf16(a0, b0v, acc[0][0], 0, 0, 0);
            acc[0][1] = __builtin_amdgcn_mfma_f32_16x16x32_bf16(a0, b1v, acc[0][1], 0, 0, 0);
            acc[1][0] = __builtin_amdgcn_mfma_f32_16x16x32_bf16(a1, b0v, acc[1][0], 0, 0, 0);
            acc[1][1] = __builtin_amdgcn_mfma_f32_16x16x32_bf16(a1, b1v, acc[1][1], 0, 0, 0);
        }
    }

    // C[t][bgrp][n][16]: bgrp = bcol>>4, within-grp batch = bcol&15
#pragma unroll
    for (int nsub = 0; nsub < 2; ++nsub) {
#pragma unroll
        for (int bsub = 0; bsub < 2; ++bsub) {
#pragma unroll
            for (int r = 0; r < 4; ++r) {
                int n = n0 + wn * 32 + nsub * 16 + kgrp * 4 + r;
                if (n < Nn) {
                    int bcol = wb * 32 + bsub * 16 + l15;
                    C[(((size_t)t * 4 + (bcol >> 4)) * Nn + n) * 16 + (bcol & 15)] =
                        f_to_bfu(acc[nsub][bsub][r] + bias[n]);
                }
            }
        }
    }
}

// ---------------- MFMA emit projection: emit[m][64] = h2 @ Wout^T + b ----------------
__global__ __launch_bounds__(256) void emit_mfma(const ushort_t* __restrict__ A,
                                                 const ushort_t* __restrict__ W,
                                                 const float* __restrict__ bias,
                                                 float* __restrict__ C) {
    const int t = blockIdx.x;
    const int tid = threadIdx.x;
    const int lane = tid & 63;
    const int wv = tid >> 6;
    const int wn = wv & 1, wb = wv >> 1;
    const int l15 = lane & 15, kgrp = lane >> 4;

    __shared__ ushort_t wlds[64 * 64];

    const int rrow = tid >> 3, kc = tid & 7;
    const int rrow2 = (tid + 256) >> 3;

    auto load_tile = [&](int k0, v8bf* nxt) {
#pragma unroll
        for (int c = 0; c < 2; ++c) {
            int rr = c ? rrow2 : rrow;
            nxt[c] = *(const v8bf*)(W + (size_t)rr * 1024 + k0 + kc * 8);
        }
    };

    f32x4 acc[2][2] = {};
    v8bf nxt[2];
    load_tile(0, nxt);

    for (int k0 = 0; k0 < 1024; k0 += 64) {
        if (k0) __syncthreads();
#pragma unroll
        for (int c = 0; c < 2; ++c) {
            int rr = c ? rrow2 : rrow;
            int off = (rr * 128 + kc * 16) ^ ((rr & 7) << 4);
            *(v8bf*)((char*)wlds + off) = nxt[c];
        }
        __syncthreads();
        if (k0 + 64 < 1024) load_tile(k0 + 64, nxt);

#pragma unroll
        for (int ks = 0; ks < 2; ++ks) {
            int kk = k0 + ks * 32 + kgrp * 8;
            int dir = kk >> 9, kr = kk & 511;
            int br0 = wb * 32 + l15;
            const ushort_t* pb0 = A + (((size_t)(dir * B_ + br0) * S_) + t) * 512 + kr;
            const ushort_t* pb1 = A + (((size_t)(dir * B_ + br0 + 16) * S_) + t) * 512 + kr;
            v8bf b0v = *(const v8bf*)pb0;
            v8bf b1v = *(const v8bf*)pb1;
            int r0 = wn * 32 + l15;
            int aoff0 = (r0 * 128 + ks * 64 + kgrp * 16) ^ ((r0 & 7) << 4);
            int aoff1 = ((r0 + 16) * 128 + ks * 64 + kgrp * 16) ^ ((r0 & 7) << 4);
            v8bf a0 = *(const v8bf*)((const char*)wlds + aoff0);
            v8bf a1 = *(const v8bf*)((const char*)wlds + aoff1);
            acc[0][0] = __builtin_amdgcn_mfma_f32_16x16x32_bf16(a0, b0v, acc[0][0], 0, 0, 0);
            acc[0][1] = __builtin_amdgcn_mfma_f32_16x16x32_bf16(a0, b1v, acc[0][1], 0, 0, 0);
            acc[1][0] = __builtin_amdgcn_mfma_f32_16x16x32_bf16(a1, b0v, acc[1][0], 0, 0, 0);
            acc[1][1] = __builtin_amdgcn_mfma_f32_16x16x32_bf16(a1, b1v, acc[1][1], 0, 0, 0);
        }
    }

#pragma unroll
    for (int nsub = 0; nsub < 2; ++nsub) {
#pragma unroll
        for (int bsub = 0; bsub < 2; ++bsub) {
            int n = wn * 32 + nsub * 16 + kgrp * 4;
            int bcol = wb * 32 + bsub * 16 + l15;
            float4 v;
            v.x = acc[nsub][bsub][0] + bias[n + 0];
            v.y = acc[nsub][bsub][1] + bias[n + 1];
            v.z = acc[nsub][bsub][2] + bias[n + 2];
            v.w = acc[nsub][bsub][3] + bias[n + 3];
            *(float4*)&C[((size_t)bcol * S_ + t) * 64 + n] = v;
        }
    }
}

// ---------------- K-split 2-wave persistent LSTM recurrence (R13 verbatim) ----------------
// grid 256 x 128 threads. Block = (dir, shard 0..31, bgrp 0..3); 2 waves split K.
// SYNC (R7-proven, fastest of 6 measured schemes): producer h-store ->
// vmcnt(0) ack -> relaxed agent flag store; consumer polls flags then loads h
// ONCE. Per-step cost ~3.5us ~= 2 serialized MALL RTs + merge + compute.
__global__ __launch_bounds__(128, 1) void lstm_wave_kernel(
        const ushort_t* __restrict__ Gf, const ushort_t* __restrict__ Gb,
        const float* __restrict__ Whh_f, const float* __restrict__ Whh_b,
        ushort_t* __restrict__ hseq,
        int* __restrict__ flags) {
    const int bid = blockIdx.x;
    const int dir = bid >> 7;
    const int shard = (bid >> 2) & 31;
    const int bgrp = bid & 3;
    const int tid = threadIdx.x;
    const int w = tid >> 6;             // K-half
    const int lane = tid & 63;
    const int l15 = lane & 15, kgrp = lane >> 4;
    const int batch = bgrp * 16 + l15;
    const int n0c = shard * 16;
    const int domain = dir * 4 + bgrp;

    const ushort_t* G = dir ? Gb : Gf;
    const float* Whh = dir ? Whh_b : Whh_f;

    __shared__ float xlds[2][16][64];

    v8bf wreg[4][8];
    {
        int g = l15 & 3;
        int colbase = n0c + (l15 >> 2) * 4;
#pragma unroll
        for (int j = 0; j < 4; ++j) {
            int col = colbase + j;
            bool cok = col < H_;
            const float* wrow = Whh + ((size_t)g * H_ + (cok ? col : 0)) * H_;
#pragma unroll
            for (int ki = 0; ki < 8; ++ki) {
                union { ushort_t u[8]; v8bf v; } tmp;
#pragma unroll
                for (int e = 0; e < 8; ++e) {
                    int k = w * 256 + ki * 32 + kgrp * 8 + e;
                    tmp.u[e] = (cok && k < H_) ? f_to_bfu(wrow[k]) : (ushort_t)0;
                }
                wreg[j][ki] = tmp.v;
            }
        }
    }

    float c[4] = {0.f, 0.f, 0.f, 0.f};

    for (int s = 0; s < S_; ++s) {
        const int tr = dir ? (S_ - 1 - s) : s;

        float p[4][4];
        if (w == 0) {
#pragma unroll
            for (int j = 0; j < 4; ++j) {
                int col = n0c + kgrp * 4 + j;
                int colc = (col < H_) ? col : (H_ - 1);
#pragma unroll
                for (int g = 0; g < 4; ++g)
                    p[j][g] = bfu_to_f(G[(((size_t)tr * 4 + bgrp) * 2000 + g * H_ + colc) * 16 + l15]);
            }
        }
        asm volatile("" ::: "memory");

        f32x4 acc[4] = {};
        if (s > 0) {
            {
                const int need = s;
                int fi = domain * 32 + w * 16 + (lane & 15);
                while (true) {
                    int f = (lane < 16)
                        ? __hip_atomic_load(&flags[fi], __ATOMIC_RELAXED, __HIP_MEMORY_SCOPE_AGENT)
                        : need;
                    if (__all(f >= need)) break;
                    __builtin_amdgcn_s_sleep(1);
                }
            }
            asm volatile("" ::: "memory");

            const int trp = dir ? (tr + 1) : (tr - 1);
            const ushort_t* hrow = hseq + (((size_t)dir * B_ + batch) * S_ + trp) * 512 + w * 256;
            v8bf bfr[8];
#pragma unroll
            for (int ki = 0; ki < 8; ++ki)
                bfr[ki] = load16_coh(hrow + ki * 32 + kgrp * 8);
            asm volatile("s_waitcnt vmcnt(0)" ::: "memory");
            __builtin_amdgcn_sched_barrier(0);   // rule-18: no MFMA hoist above the wait

#pragma unroll
            for (int ki = 0; ki < 8; ++ki)
#pragma unroll
                for (int j = 0; j < 4; ++j)
                    acc[j] = __builtin_amdgcn_mfma_f32_16x16x32_bf16(wreg[j][ki], bfr[ki], acc[j], 0, 0, 0);
        }

        if (w == 1) {
#pragma unroll
            for (int j = 0; j < 4; ++j)
#pragma unroll
                for (int r = 0; r < 4; ++r)
                    xlds[s & 1][j * 4 + r][lane] = acc[j][r];
        }
        __syncthreads();

        if (w == 0) {
            ushort_t hv[4];
#pragma unroll
            for (int j = 0; j < 4; ++j) {
                float gi = p[j][0] + acc[j][0] + xlds[s & 1][j * 4 + 0][lane];
                float gf = p[j][1] + acc[j][1] + xlds[s & 1][j * 4 + 1][lane];
                float gg = p[j][2] + acc[j][2] + xlds[s & 1][j * 4 + 2][lane];
                float go = p[j][3] + acc[j][3] + xlds[s & 1][j * 4 + 3][lane];
                c[j] = sigm(gf) * c[j] + sigm(gi) * tanh_fast(gg);
                hv[j] = f_to_bfu(sigm(go) * tanh_fast(c[j]));
            }
            int colb = n0c + kgrp * 4;
            if (colb < H_) {
                uint2 pk;
                pk.x = (unsigned)hv[0] | ((unsigned)hv[1] << 16);
                pk.y = (unsigned)hv[2] | ((unsigned)hv[3] << 16);
                store8_coh(hseq + (((size_t)dir * B_ + batch) * S_ + tr) * 512 + colb, pk);
            }
            asm volatile("s_waitcnt vmcnt(0)" ::: "memory");
            if (lane == 0)
                __hip_atomic_store(&flags[domain * 32 + shard], s + 1,
                                   __ATOMIC_RELAXED, __HIP_MEMORY_SCOPE_AGENT);
        }
    }
}

// ---------------- CRF: partition + gold score, one block per batch ----------------
__global__ __launch_bounds__(256) void crf_kernel(const float* __restrict__ emit,
                                                  const float* __restrict__ trans,
                                                  const int* __restrict__ x,
                                                  const int* __restrict__ y0,
                                                  float* __restrict__ out) {
    const int b = blockIdx.x, tid = threadIdx.x;
    __shared__ float tr[64][65];
    __shared__ float sc[2][64];
    __shared__ float zsh;
    __shared__ float red[4];

    for (int e = tid; e < 4096; e += 256) tr[e >> 6][e & 63] = trans[e];
    if (tid < 64) sc[0][tid] = (tid == SOS_) ? 0.f : -10000.f;
    __syncthreads();

    const int i = tid >> 2, sub = tid & 3;
    int cur = 0;
    for (int t = 0; t < S_; ++t) {
        int m = x[b * S_ + t] > 0;
        float v[16];
        float vmax = -3.0e38f;
#pragma unroll
        for (int jj = 0; jj < 16; ++jj) {
            int j = (sub << 4) + jj;
            v[jj] = sc[cur][j] + tr[i][j];
            vmax = fmaxf(vmax, v[jj]);
        }
        vmax = fmaxf(vmax, __shfl_xor(vmax, 1, 64));
        vmax = fmaxf(vmax, __shfl_xor(vmax, 2, 64));
        float s = 0.f;
#pragma unroll
        for (int jj = 0; jj < 16; ++jj) s += __expf(v[jj] - vmax);
        s += __shfl_xor(s, 1, 64);
        s += __shfl_xor(s, 2, 64);
        float lse = vmax + __logf(s);
        float e_i = emit[((size_t)b * S_ + t) * NT_ + i];
        if (sub == 0) sc[cur ^ 1][i] = m ? (lse + e_i) : sc[cur][i];
        __syncthreads();
        cur ^= 1;
    }

    if (tid < 64) {
        float v2 = sc[cur][tid];
        float mz = v2;
        for (int d = 1; d < 64; d <<= 1) mz = fmaxf(mz, __shfl_xor(mz, d, 64));
        float sz = __expf(v2 - mz);
        for (int d = 1; d < 64; d <<= 1) sz += __shfl_xor(sz, d, 64);
        if (tid == 0) zsh = mz + __logf(sz);
    }
    __syncthreads();

    {
        int t = tid;
        int m = x[b * S_ + t] > 0;
        int yc = y0[b * S_ + t];
        int yp = t ? y0[b * S_ + t - 1] : SOS_;
        float term = m ? (emit[((size_t)b * S_ + t) * NT_ + yc] + tr[yc][yp]) : 0.f;
        for (int d = 1; d < 64; d <<= 1) term += __shfl_xor(term, d, 64);
        if ((tid & 63) == 0) red[tid >> 6] = term;
    }
    __syncthreads();
    if (tid == 0) out[b] = zsh - (red[0] + red[1] + red[2] + red[3]);
}

// ---------------- launcher ----------------
extern "C" void kernel_launch(void* const* d_in, const int* in_sizes, int n_in,
                              void* d_out, int out_size, void* d_ws, size_t ws_size,
                              hipStream_t stream) {
    const int* x = (const int*)d_in[0];
    const int* y0 = (const int*)d_in[1];
    const float* embed = (const float*)d_in[2];
    const float* w_ih_l0f = (const float*)d_in[3];
    const float* w_hh_l0f = (const float*)d_in[4];
    const float* b_l0f = (const float*)d_in[5];
    const float* w_ih_l0b = (const float*)d_in[6];
    const float* w_hh_l0b = (const float*)d_in[7];
    const float* b_l0b = (const float*)d_in[8];
    const float* w_ih_l1f = (const float*)d_in[9];
    const float* w_hh_l1f = (const float*)d_in[10];
    const float* b_l1f = (const float*)d_in[11];
    const float* w_ih_l1b = (const float*)d_in[12];
    const float* w_hh_l1b = (const float*)d_in[13];
    const float* b_l1b = (const float*)d_in[14];
    const float* W_out = (const float*)d_in[15];
    const float* b_out = (const float*)d_in[16];
    const float* trans = (const float*)d_in[17];
    float* outp = (float*)d_out;

    char* ws = (char*)d_ws;
    size_t off = 0;
    auto alloc = [&](size_t bytes) {
        void* p = ws + off;
        off += (bytes + 255) & ~(size_t)255;
        return p;
    };
    ushort_t* h0 = (ushort_t*)alloc((size_t)B_ * S_ * 320 * 2);            // 10.5 MB
    ushort_t* hseq = (ushort_t*)alloc((size_t)2 * B_ * S_ * 512 * 2);      // 33.6 MB
    float* emitb = (float*)alloc((size_t)B_ * S_ * NT_ * 4);               // 4.2 MB
    ushort_t* Gf = (ushort_t*)alloc((size_t)S_ * 2000 * 64 * 2);           // 65.5 MB [t][4][2000][16]
    ushort_t* Gb = (ushort_t*)alloc((size_t)S_ * 2000 * 64 * 2);           // 65.5 MB
    int* flags = (int*)alloc((size_t)2 * 256 * 4);                         // 2 KB
    (void)in_sizes; (void)n_in; (void)out_size;

    // aliased weight buffers (disjoint lifetimes):
    ushort_t* Wl0f = (ushort_t*)emitb;
    ushort_t* Wl0b = Wl0f + (size_t)2000 * 320;
    ushort_t* Wl1f = (ushort_t*)h0;
    ushort_t* Wl1b = Wl1f + (size_t)2000 * 1024;
    ushort_t* Wout = Wl1b + (size_t)2000 * 1024;

    if (off > ws_size) {
        dbg_kernel<<<1, 64, 0, stream>>>(outp, (float)(ws_size / 1048576.0));
        return;
    }

    const int M = B_ * S_;

    hipMemsetAsync(flags, 0, (size_t)2 * 256 * 4, stream);
    hipMemsetAsync(hseq, 0, (size_t)2 * B_ * S_ * 512 * 2, stream);  // pads must be 0

    gather_kernel<<<M, 128, 0, stream>>>(x, embed, h0);

    {
        int tot = 2000 * 320, nb = (tot + 255) / 256;
        conv_w_kernel<<<nb, 256, 0, stream>>>(w_ih_l0f, Wl0f, 2000, 320, 300, 320, 300);
        conv_w_kernel<<<nb, 256, 0, stream>>>(w_ih_l0b, Wl0b, 2000, 320, 300, 320, 300);
    }

    // layer 0 input GEMM (MFMA): G[t][bgrp][n][16]
    gemm_mfma<0><<<dim3(S_, 32, 2), 256, 0, stream>>>(
        h0, Wl0f, Wl0b, b_l0f, b_l0b, Gf, Gb, 2000, 320);

    {
        int tot = 2000 * 1024, nb = (tot + 255) / 256;
        conv_w_kernel<<<nb, 256, 0, stream>>>(w_ih_l1f, Wl1f, 2000, 1024, 1000, 512, 500);
        conv_w_kernel<<<nb, 256, 0, stream>>>(w_ih_l1b, Wl1b, 2000, 1024, 1000, 512, 500);
        int tot2 = 64 * 1024, nb2 = (tot2 + 255) / 256;
        conv_w_kernel<<<nb2, 256, 0, stream>>>(W_out, Wout, 64, 1024, 1000, 512, 500);
    }

    // layer 0 recurrence (R13 config, ack+flag sync)
    lstm_wave_kernel<<<256, 128, 0, stream>>>(Gf, Gb, w_hh_l0f, w_hh_l0b, hseq, flags);

    // layer 1 input GEMM (MFMA, consumes layer-0 hseq)
    gemm_mfma<1><<<dim3(S_, 32, 2), 256, 0, stream>>>(
        hseq, Wl1f, Wl1b, b_l1f, b_l1b, Gf, Gb, 2000, 1024);

    // layer 1 recurrence (separate flag region)
    lstm_wave_kernel<<<256, 128, 0, stream>>>(Gf, Gb, w_hh_l1f, w_hh_l1b, hseq, flags + 256);

    // emit projection (MFMA, fp32 out)
    emit_mfma<<<S_, 256, 0, stream>>>(hseq, Wout, b_out, emitb);

    crf_kernel<<<B_, 256, 0, stream>>>(emitb, trans, x, y0, outp);
}